// Round 12
// baseline (494.844 us; speedup 1.0000x reference)
//
#include <hip/hip_runtime.h>
#include <hip/hip_bf16.h>
#include <math.h>

// B=4, S=2048, D_MODEL=1024, H=16, HD=32, SCALE=8.0
typedef unsigned short u16;
typedef unsigned int u32;
typedef unsigned long long u64;
typedef __attribute__((ext_vector_type(8))) short s16x8;
typedef __attribute__((ext_vector_type(4))) short s16x4;
typedef __attribute__((ext_vector_type(4))) float f32x4;
typedef __attribute__((ext_vector_type(16))) float f32x16;
typedef __attribute__((ext_vector_type(2))) unsigned int u32x2;

#define DEV static __device__ __forceinline__

DEV u16 f2bf(float f){
  __hip_bfloat16 h = __float2bfloat16(f);
  return *reinterpret_cast<u16*>(&h);
}

DEV u32 cvt_pk_bf16(float lo, float hi_){
  u32 r;
  asm("v_cvt_pk_bf16_f32 %0, %1, %2" : "=v"(r) : "v"(lo), "v"(hi_));
  return r;  // low16 = bf16(lo), high16 = bf16(hi_)
}

// SSA-clean permlane32 swap: returns {a.lo||b.lo, a.hi||b.hi} (verified R3->R4 pass)
DEV u32x2 pl32swap(u32 a, u32 b){
  return __builtin_amdgcn_permlane32_swap(a, b, false, false);
}
DEV float xhalf_sum(float x){
  u32x2 r = pl32swap(__float_as_uint(x), __float_as_uint(x));
  return __uint_as_float(r[0]) + __uint_as_float(r[1]);
}

// masked-zero: ext = sext(bit CPOS of msn) (msn = ~mask, so unmasked -> -1 keep, masked -> 0)
template<int CPOS> DEV float mzero(float p, u32 msn){
  int ext;
  asm("v_bfe_i32 %0, %1, %2, 1" : "=v"(ext) : "v"(msn), "n"(CPOS));
  return __uint_as_float(__float_as_uint(p) & (u32)ext);
}

// async global->LDS, 16B per lane; LDS dest = wave-uniform base + lane*16, global src per-lane
DEV void gload16(const u16* g, u16* l){
  __builtin_amdgcn_global_load_lds((const __attribute__((address_space(1))) void*)g,
                                   (__attribute__((address_space(3))) void*)l, 16, 0, 0);
}

// ---------------- mask dtype detect ----------------
__global__ void detect_mask_kernel(const unsigned char* __restrict__ m, int* __restrict__ flag){
  __shared__ int cnt;
  if (threadIdx.x==0) cnt=0;
  __syncthreads();
  int nz=0;
  for (int i=threadIdx.x;i<4096;i+=256) nz += (m[(size_t)i*4+1]!=0)?1:0;
  if (nz) atomicAdd(&cnt, nz);
  __syncthreads();
  if (threadIdx.x==0) *flag = (cnt==0)?4:1;   // 4: int32 mask (LSB), 1: bool/uint8
}

// ---------------- mask bit-pack: 16 elements per thread -> u16 word ----------------
__global__ __launch_bounds__(256) void pack_mask_kernel(const unsigned char* __restrict__ m,
    const int* __restrict__ flag, u16* __restrict__ mb16){
  const int stride = *flag;
  const size_t gid = (size_t)blockIdx.x*256u + threadIdx.x;   // 1,048,576 threads
  u32 bits = 0;
  if (stride == 1){
    const uint4 v = *(const uint4*)(m + gid*16);
    bits  =  ((v.x & 0x01010101u) * 0x01020408u) >> 24;
    bits |= (((v.y & 0x01010101u) * 0x01020408u) >> 24) << 4;
    bits |= (((v.z & 0x01010101u) * 0x01020408u) >> 24) << 8;
    bits |= (((v.w & 0x01010101u) * 0x01020408u) >> 24) << 12;
  } else {
    const unsigned char* mm = m + gid*64;
    const uint4 a = *(const uint4*)(mm);
    const uint4 b = *(const uint4*)(mm+16);
    const uint4 c = *(const uint4*)(mm+32);
    const uint4 d = *(const uint4*)(mm+48);
    bits  = (u32)(a.x!=0) | ((u32)(a.y!=0)<<1) | ((u32)(a.z!=0)<<2) | ((u32)(a.w!=0)<<3)
          | ((u32)(b.x!=0)<<4) | ((u32)(b.y!=0)<<5) | ((u32)(b.z!=0)<<6) | ((u32)(b.w!=0)<<7)
          | ((u32)(c.x!=0)<<8) | ((u32)(c.y!=0)<<9) | ((u32)(c.z!=0)<<10)| ((u32)(c.w!=0)<<11)
          | ((u32)(d.x!=0)<<12)| ((u32)(d.y!=0)<<13)| ((u32)(d.z!=0)<<14)| ((u32)(d.w!=0)<<15);
  }
  mb16[gid] = (u16)bits;
}

// ---------------- weight prep: bf16 + [n][k] transpose; Wq pre-scaled by 0.125*log2(e) ----------------
__global__ __launch_bounds__(256) void prep_weights_kernel(
    const float* __restrict__ Wq, const float* __restrict__ Wk, const float* __restrict__ Wv,
    const float* __restrict__ Wo, u16* __restrict__ WT, u16* __restrict__ WoT){
  int gid = blockIdx.x*256 + threadIdx.x;
  if (gid < 3*512*1024){
    int z = gid >> 19;
    int r = gid & ((1<<19)-1);
    int n = r >> 10, d = r & 1023;
    const float* W = (z==0)?Wq:((z==1)?Wk:Wv);
    int h = n>>5, e = n&31;
    float wv = W[((size_t)h*1024 + (size_t)d)*32 + e];
    if (z==0) wv *= 0.18033688011112042f;   // (1/sqrt(64)) * log2(e)
    WT[gid] = f2bf(wv);
  } else {
    int r = gid - 3*512*1024;
    int n = r >> 9, cc = r & 511;
    WoT[r] = f2bf(Wo[(size_t)cc*1024 + n]);
  }
}

// ---------------- projection GEMM: [8192x1024]f32 x WT[n][k] -> Q/K (bf16 [B,H,S,32]) or V^T (bf16 [B,H,32,S])
__global__ __launch_bounds__(256) void gemm_proj_kernel(
    const float* __restrict__ Aq, const float* __restrict__ Ak, const float* __restrict__ Av,
    const u16* __restrict__ WT, u16* __restrict__ Qp, u16* __restrict__ Kp, u16* __restrict__ Vt)
{
  __shared__ u16 As[128*64];
  __shared__ u16 Bs[128*64];
  const int z = blockIdx.z;
  const float* __restrict__ A = (z==0)?Aq:((z==1)?Ak:Av);
  const u16* __restrict__ W = WT + (size_t)z*(512*1024);
  const int m0 = blockIdx.x*128, n0 = blockIdx.y*128;
  const int t = threadIdx.x, lane = t&63, wv = t>>6;
  const int wr = wv>>1, wc = wv&1;
  const int c = lane&15, g = lane>>4;
  f32x4 acc[4][4] = {};
  for (int kk=0; kk<1024; kk+=64){
    #pragma unroll
    for (int j=0;j<8;j++){                       // A: 128x64 f32 -> bf16 LDS (swizzled), cvt_pk packing
      int idx = t + j*256;
      int row = idx>>4, kq=(idx&15)<<2;
      f32x4 a4 = *(const f32x4*)(A + (size_t)(m0+row)*1024 + kk + kq);
      u32x2 w2;
      w2[0] = cvt_pk_bf16(a4[0], a4[1]);
      w2[1] = cvt_pk_bf16(a4[2], a4[3]);
      int co = (kq<<1) ^ ((row&7)<<4);
      *(u32x2*)((char*)As + row*128 + co) = w2;
    }
    #pragma unroll
    for (int j=0;j<4;j++){                       // B: 128x64 bf16
      int idx = t + j*256;
      int n = idx>>3, k8=(idx&7)<<3;
      s16x8 bv = *(const s16x8*)(W + (size_t)(n0+n)*1024 + kk + k8);
      int co = (k8<<1) ^ ((n&7)<<4);
      *(s16x8*)((char*)Bs + n*128 + co) = bv;
    }
    __syncthreads();
    #pragma unroll
    for (int ks=0;ks<2;ks++){
      s16x8 af[4], bf[4];
      #pragma unroll
      for (int i=0;i<4;i++){
        int ra = wr*64 + i*16 + c;
        af[i] = *(const s16x8*)((const char*)As + ra*128 + ((ks*64 + g*16) ^ ((ra&7)<<4)));
        int rb = wc*64 + i*16 + c;
        bf[i] = *(const s16x8*)((const char*)Bs + rb*128 + ((ks*64 + g*16) ^ ((rb&7)<<4)));
      }
      #pragma unroll
      for (int mi=0;mi<4;mi++)
        #pragma unroll
        for (int nj=0;nj<4;nj++)
          acc[mi][nj] = __builtin_amdgcn_mfma_f32_16x16x32_bf16(af[mi], bf[nj], acc[mi][nj], 0, 0, 0);
    }
    __syncthreads();
  }
  #pragma unroll
  for (int mi=0;mi<4;mi++){
    #pragma unroll
    for (int nj=0;nj<4;nj++){
      #pragma unroll
      for (int r=0;r<4;r++){
        int gm = m0 + wr*64 + mi*16 + g*4 + r;
        int gn = n0 + wc*64 + nj*16 + c;
        u16 val = f2bf(acc[mi][nj][r]);
        int b = gm>>11, s = gm&2047, hh = gn>>5, e = gn&31;
        if (z==0)      Qp[((size_t)(b*16+hh)*2048 + s)*32 + e] = val;
        else if (z==1) Kp[((size_t)(b*16+hh)*2048 + s)*32 + e] = val;
        else           Vt[((size_t)(b*16+hh)*32 + e)*2048 + s] = val;
      }
    }
  }
}

// ---------------- flash attention: R7 dual-chain body + LDS-staged K/V (double-buffered, 1-ahead) ----------
// All 4 waves of a block share the same bh -> same K/V tiles. Stage them ONCE per block into LDS in
// fragment order (lane l's 16B at lds+l*16; permutation applied on per-lane GLOBAL src address, LDS
// dest linear as global_load_lds requires). Double buffer, prefetch next iteration during compute;
// one vmcnt(0)+barrier per iteration after a full compute phase (drain ~free).
__global__ __launch_bounds__(256, 4) void attn_kernel(
    const u16* __restrict__ Qp, const u16* __restrict__ Kp, const u16* __restrict__ Vt,
    const u32* __restrict__ mb32, u16* __restrict__ Z)
{
  __shared__ u16 KV[2][8][512];      // [buf][frag][lane*8] : frags 0-3 = K(A0,A1,B0,B1), 4-7 = V(A0,A1,B0,B1)
  __shared__ float Osh[4][32][36];
  const int t = threadIdx.x, lane = t&63, wid = t>>6;
  const int c = lane&31, hi = lane>>5;
  const int hi8 = hi*8;
  // XCD-aware swizzle: all 16 q-tiles of one bh land on one XCD
  const int wg = blockIdx.x;            // 0..1023
  const int xcd = wg & 7, loc = wg >> 3;
  const int bh = xcd*8 + (loc>>4);
  const int qb = loc & 15;
  const int b = bh>>4, h = bh&15;
  const int q0 = qb*128 + wid*32;
  const u16* Qh = Qp + (size_t)bh*2048*32;
  const u16* Kh = Kp + (size_t)bh*2048*32;
  const u16* Vh = Vt + (size_t)bh*32*2048;

  // Q B-frag: col=q=c, k-dim = hd  (Q pre-scaled by 0.125*log2e)
  const s16x8 qf0 = *(const s16x8*)(Qh + (size_t)(q0 + c)*32 + hi8);
  const s16x8 qf1 = *(const s16x8*)(Qh + (size_t)(q0 + c)*32 + 16 + hi8);

  const f32x16 z16 = {0,0,0,0,0,0,0,0,0,0,0,0,0,0,0,0};
  f32x16 OA = z16, OB = z16;
  f32x4 LA = {0,0,0,0}, LB = {0,0,0,0};
  const u32* mrowp = mb32 + ((size_t)b*2048 + (size_t)(q0 + c))*64;  // 64 u32 words per q-row

  // stage iteration `it` (two 32-col tiles at kb, kb+32) into KV[buf]; each wave issues 2 frags
  auto stage = [&](int it, int buf){
    const int kb = it*64;
    #pragma unroll
    for (int j=0;j<2;j++){
      const int f = wid*2 + j;           // waves 0,1 -> K frags 0-3; waves 2,3 -> V frags 4-7
      const int X = (f>>1)&1, s = f&1;
      const u16* g = (f < 4)
        ? (Kh + (size_t)(kb + X*32 + c)*32 + s*16 + hi8)
        : (Vh + (size_t)c*2048 + (kb + X*32 + s*16 + hi8));
      gload16(g, &KV[buf][f][0]);
    }
  };

  stage(0, 0);
  asm volatile("s_waitcnt vmcnt(0)" ::: "memory");
  __syncthreads();

  for (int it = 0; it < 32; ++it){
    const int cur = it & 1;
    if (it + 1 < 32) stage(it + 1, cur ^ 1);
    const u64 mw = *(const u64*)(mrowp + it*2);
    const u32 msnA = ~(((u32)mw) >> (4*hi));
    const u32 msnB = ~(((u32)(mw >> 32)) >> (4*hi));

    // fragments from LDS (conflict-free: lane l reads bytes [l*16, l*16+16) of a 1KB region)
    const u16* kv = &KV[cur][0][0];
    const s16x8 kfA0 = *(const s16x8*)(kv + 0*512 + lane*8);
    const s16x8 kfA1 = *(const s16x8*)(kv + 1*512 + lane*8);
    const s16x8 kfB0 = *(const s16x8*)(kv + 2*512 + lane*8);
    const s16x8 kfB1 = *(const s16x8*)(kv + 3*512 + lane*8);
    const s16x8 vfA0 = *(const s16x8*)(kv + 4*512 + lane*8);
    const s16x8 vfA1 = *(const s16x8*)(kv + 5*512 + lane*8);
    const s16x8 vfB0 = *(const s16x8*)(kv + 6*512 + lane*8);
    const s16x8 vfB1 = *(const s16x8*)(kv + 7*512 + lane*8);

    // ---- QK^T (swapped): independent accumulator chains ----
    __builtin_amdgcn_s_setprio(1);
    f32x16 pA = __builtin_amdgcn_mfma_f32_32x32x16_bf16(kfA0, qf0, z16, 0, 0, 0);
    pA = __builtin_amdgcn_mfma_f32_32x32x16_bf16(kfA1, qf1, pA, 0, 0, 0);
    f32x16 pB = __builtin_amdgcn_mfma_f32_32x32x16_bf16(kfB0, qf0, z16, 0, 0, 0);
    pB = __builtin_amdgcn_mfma_f32_32x32x16_bf16(kfB1, qf1, pB, 0, 0, 0);
    __builtin_amdgcn_s_setprio(0);

    // p = exp2(s); zero masked (bit of msn==0 -> masked -> 0)
    #define MZE(P,R,MS) P[R] = mzero<(((R)&3)+8*((R)>>2))>(__builtin_amdgcn_exp2f(P[R]), MS)
    MZE(pA,0,msnA);  MZE(pA,1,msnA);  MZE(pA,2,msnA);  MZE(pA,3,msnA);
    MZE(pA,4,msnA);  MZE(pA,5,msnA);  MZE(pA,6,msnA);  MZE(pA,7,msnA);
    MZE(pA,8,msnA);  MZE(pA,9,msnA);  MZE(pA,10,msnA); MZE(pA,11,msnA);
    MZE(pA,12,msnA); MZE(pA,13,msnA); MZE(pA,14,msnA); MZE(pA,15,msnA);
    MZE(pB,0,msnB);  MZE(pB,1,msnB);  MZE(pB,2,msnB);  MZE(pB,3,msnB);
    MZE(pB,4,msnB);  MZE(pB,5,msnB);  MZE(pB,6,msnB);  MZE(pB,7,msnB);
    MZE(pB,8,msnB);  MZE(pB,9,msnB);  MZE(pB,10,msnB); MZE(pB,11,msnB);
    MZE(pB,12,msnB); MZE(pB,13,msnB); MZE(pB,14,msnB); MZE(pB,15,msnB);
    #undef MZE

    // ---- l partial sums via VALU (off critical path, 4 accumulators per chain) ----
    #pragma unroll
    for (int i=0;i<4;i++){
      LA[i] += (pA[i] + pA[i+4]) + (pA[i+8] + pA[i+12]);
      LB[i] += (pB[i] + pB[i+4]) + (pB[i+8] + pB[i+12]);
    }

    // ---- P^T B-frags: cvt_pk pairs + permlane swaps (wiring verified R3/R4) ----
    u32 pwA0 = cvt_pk_bf16(pA[0],  pA[1]);
    u32 pwA1 = cvt_pk_bf16(pA[2],  pA[3]);
    u32 pwA2 = cvt_pk_bf16(pA[4],  pA[5]);
    u32 pwA3 = cvt_pk_bf16(pA[6],  pA[7]);
    u32 pwA4 = cvt_pk_bf16(pA[8],  pA[9]);
    u32 pwA5 = cvt_pk_bf16(pA[10], pA[11]);
    u32 pwA6 = cvt_pk_bf16(pA[12], pA[13]);
    u32 pwA7 = cvt_pk_bf16(pA[14], pA[15]);
    u32x2 a02 = pl32swap(pwA0, pwA2);
    u32x2 a13 = pl32swap(pwA1, pwA3);
    u32x2 a46 = pl32swap(pwA4, pwA6);
    u32x2 a57 = pl32swap(pwA5, pwA7);
    union { u32 u[4]; s16x8 v; } fA0 = {{a02[0], a13[0], a02[1], a13[1]}};
    union { u32 u[4]; s16x8 v; } fA1 = {{a46[0], a57[0], a46[1], a57[1]}};
    u32 pwB0 = cvt_pk_bf16(pB[0],  pB[1]);
    u32 pwB1 = cvt_pk_bf16(pB[2],  pB[3]);
    u32 pwB2 = cvt_pk_bf16(pB[4],  pB[5]);
    u32 pwB3 = cvt_pk_bf16(pB[6],  pB[7]);
    u32 pwB4 = cvt_pk_bf16(pB[8],  pB[9]);
    u32 pwB5 = cvt_pk_bf16(pB[10], pB[11]);
    u32 pwB6 = cvt_pk_bf16(pB[12], pB[13]);
    u32 pwB7 = cvt_pk_bf16(pB[14], pB[15]);
    u32x2 b02 = pl32swap(pwB0, pwB2);
    u32x2 b13 = pl32swap(pwB1, pwB3);
    u32x2 b46 = pl32swap(pwB4, pwB6);
    u32x2 b57 = pl32swap(pwB5, pwB7);
    union { u32 u[4]; s16x8 v; } fB0 = {{b02[0], b13[0], b02[1], b13[1]}};
    union { u32 u[4]; s16x8 v; } fB1 = {{b46[0], b57[0], b46[1], b57[1]}};

    // ---- PV: independent accumulators ----
    __builtin_amdgcn_s_setprio(1);
    OA = __builtin_amdgcn_mfma_f32_32x32x16_bf16(vfA0, fA0.v, OA, 0, 0, 0);
    OA = __builtin_amdgcn_mfma_f32_32x32x16_bf16(vfA1, fA1.v, OA, 0, 0, 0);
    OB = __builtin_amdgcn_mfma_f32_32x32x16_bf16(vfB0, fB0.v, OB, 0, 0, 0);
    OB = __builtin_amdgcn_mfma_f32_32x32x16_bf16(vfB1, fB1.v, OB, 0, 0, 0);
    __builtin_amdgcn_s_setprio(0);

    // staged buffer for it+1 must be complete; also guards re-staging of KV[cur] next iteration
    asm volatile("s_waitcnt vmcnt(0)" ::: "memory");
    __syncthreads();
  }

  // epilogue: merge chains, total l, normalize, transpose via LDS, store
  const float lown = ((LA[0]+LB[0]) + (LA[1]+LB[1])) + ((LA[2]+LB[2]) + (LA[3]+LB[3]));
  const float linv = 1.0f / xhalf_sum(lown);
  #pragma unroll
  for (int r=0;r<16;r++){
    const int hd = (r&3) + 8*(r>>2) + 4*hi;
    Osh[wid][c][hd] = (OA[r] + OB[r]) * linv;
  }
  __syncthreads();
  const int rq = lane >> 1, rc0 = (lane & 1)*16;
  const float* orow = &Osh[wid][rq][0];
  union { u16 q[8]; s16x8 v; } o0, o1;
  #pragma unroll
  for (int j=0;j<8;j++){ o0.q[j] = f2bf(orow[rc0+j]); o1.q[j] = f2bf(orow[rc0+8+j]); }
  u16* zp = Z + ((size_t)b*2048 + (size_t)(q0 + rq))*512 + h*32 + rc0;
  *(s16x8*)(zp)   = o0.v;
  *(s16x8*)(zp+8) = o1.v;
}

// ---------------- output GEMM: Z[8192x512]bf16 x WoT[1024][512] -> out f32 ----------------
__global__ __launch_bounds__(256) void gemm_out_kernel(
    const u16* __restrict__ Zb, const u16* __restrict__ WoT, float* __restrict__ out)
{
  __shared__ u16 As[128*64];
  __shared__ u16 Bs[128*64];
  const int m0 = blockIdx.x*128, n0 = blockIdx.y*128;
  const int t = threadIdx.x, lane=t&63, wv=t>>6;
  const int wr=wv>>1, wc=wv&1, c=lane&15, g=lane>>4;
  f32x4 acc[4][4] = {};
  for (int kk=0; kk<512; kk+=64){
    #pragma unroll
    for (int j=0;j<4;j++){
      int idx = t + j*256;
      int row = idx>>3, k8=(idx&7)<<3;
      int co = (k8<<1) ^ ((row&7)<<4);
      s16x8 av = *(const s16x8*)(Zb + (size_t)(m0+row)*512 + kk + k8);
      *(s16x8*)((char*)As + row*128 + co) = av;
      s16x8 bv = *(const s16x8*)(WoT + (size_t)(n0+row)*512 + kk + k8);
      *(s16x8*)((char*)Bs + row*128 + co) = bv;
    }
    __syncthreads();
    #pragma unroll
    for (int ks=0;ks<2;ks++){
      s16x8 af[4], bf[4];
      #pragma unroll
      for (int i=0;i<4;i++){
        int ra = wr*64 + i*16 + c;
        af[i] = *(const s16x8*)((const char*)As + ra*128 + ((ks*64 + g*16) ^ ((ra&7)<<4)));
        int rb = wc*64 + i*16 + c;
        bf[i] = *(const s16x8*)((const char*)Bs + rb*128 + ((ks*64 + g*16) ^ ((rb&7)<<4)));
      }
      #pragma unroll
      for (int mi=0;mi<4;mi++)
        #pragma unroll
        for (int nj=0;nj<4;nj++)
          acc[mi][nj] = __builtin_amdgcn_mfma_f32_16x16x32_bf16(af[mi], bf[nj], acc[mi][nj], 0, 0, 0);
    }
    __syncthreads();
  }
  #pragma unroll
  for (int mi=0;mi<4;mi++)
    #pragma unroll
    for (int nj=0;nj<4;nj++)
      #pragma unroll
      for (int r=0;r<4;r++){
        int gm = m0 + wr*64 + mi*16 + g*4 + r;
        int gn = n0 + wc*64 + nj*16 + c;
        out[(size_t)gm*1024 + gn] = acc[mi][nj][r];
      }
}

// ---------------- launcher ----------------
extern "C" void kernel_launch(void* const* d_in, const int* in_sizes, int n_in,
                              void* d_out, int out_size, void* d_ws, size_t ws_size,
                              hipStream_t stream)
{
  const float* q  = (const float*)d_in[0];
  const float* k  = (const float*)d_in[1];
  const float* v  = (const float*)d_in[2];
  const unsigned char* mask = (const unsigned char*)d_in[3];
  const float* Wq = (const float*)d_in[4];
  const float* Wk = (const float*)d_in[5];
  const float* Wv = (const float*)d_in[6];
  const float* Wo = (const float*)d_in[7];
  float* out = (float*)d_out;

  char* ws = (char*)d_ws;
  u16* Qp  = (u16*)(ws);                         //  8,388,608 B  [B,H,S,32] bf16
  u16* Kp  = (u16*)(ws + 8388608);               //  8,388,608 B
  u16* Vt  = (u16*)(ws + 16777216);              //  8,388,608 B  [B,H,32,S] bf16
  u16* Z   = (u16*)(ws + 25165824);              //  8,388,608 B  [B*S, 512] bf16
  u16* WT  = (u16*)(ws + 33554432);              //  3,145,728 B  [3][512][1024] bf16
  u16* WoT = (u16*)(ws + 36700160);              //  1,048,576 B  [1024][512] bf16
  u16* mb16 = (u16*)(ws + 37748736);             //  2,097,152 B  mask bits
  int* flag = (int*)(ws + 39845888);

  detect_mask_kernel<<<1, 256, 0, stream>>>(mask, flag);
  pack_mask_kernel<<<4096, 256, 0, stream>>>(mask, flag, mb16);
  prep_weights_kernel<<<8192, 256, 0, stream>>>(Wq, Wk, Wv, Wo, WT, WoT);
  gemm_proj_kernel<<<dim3(64,4,3), 256, 0, stream>>>(q, k, v, WT, Qp, Kp, Vt);
  attn_kernel<<<1024, 256, 0, stream>>>(Qp, Kp, Vt, (const u32*)mb16, Z);
  gemm_out_kernel<<<dim3(64,8), 256, 0, stream>>>(Z, WoT, out);
  (void)in_sizes; (void)n_in; (void)out_size; (void)ws_size;
}

// Round 13
// 207.053 us; speedup vs baseline: 2.3899x; 2.3899x over previous
//
#include <hip/hip_runtime.h>
#include <hip/hip_bf16.h>
#include <math.h>

// B=4, S=2048, D_MODEL=1024, H=16, HD=32, SCALE=8.0
typedef unsigned short u16;
typedef unsigned int u32;
typedef unsigned long long u64;
typedef __attribute__((ext_vector_type(8))) short s16x8;
typedef __attribute__((ext_vector_type(4))) short s16x4;
typedef __attribute__((ext_vector_type(4))) float f32x4;
typedef __attribute__((ext_vector_type(16))) float f32x16;
typedef __attribute__((ext_vector_type(2))) unsigned int u32x2;

#define DEV static __device__ __forceinline__

DEV u16 f2bf(float f){
  __hip_bfloat16 h = __float2bfloat16(f);
  return *reinterpret_cast<u16*>(&h);
}

DEV u32 cvt_pk_bf16(float lo, float hi_){
  u32 r;
  asm("v_cvt_pk_bf16_f32 %0, %1, %2" : "=v"(r) : "v"(lo), "v"(hi_));
  return r;  // low16 = bf16(lo), high16 = bf16(hi_)
}

// SSA-clean permlane32 swap: returns {a.lo||b.lo, a.hi||b.hi} (verified R3->R4 pass)
DEV u32x2 pl32swap(u32 a, u32 b){
  return __builtin_amdgcn_permlane32_swap(a, b, false, false);
}
DEV float xhalf_sum(float x){
  u32x2 r = pl32swap(__float_as_uint(x), __float_as_uint(x));
  return __uint_as_float(r[0]) + __uint_as_float(r[1]);
}

// masked-zero: ext = sext(bit CPOS of msn) (msn = ~mask, so unmasked -> -1 keep, masked -> 0)
template<int CPOS> DEV float mzero(float p, u32 msn){
  int ext;
  asm("v_bfe_i32 %0, %1, %2, 1" : "=v"(ext) : "v"(msn), "n"(CPOS));
  return __uint_as_float(__float_as_uint(p) & (u32)ext);
}

// ---------------- mask dtype detect ----------------
__global__ void detect_mask_kernel(const unsigned char* __restrict__ m, int* __restrict__ flag){
  __shared__ int cnt;
  if (threadIdx.x==0) cnt=0;
  __syncthreads();
  int nz=0;
  for (int i=threadIdx.x;i<4096;i+=256) nz += (m[(size_t)i*4+1]!=0)?1:0;
  if (nz) atomicAdd(&cnt, nz);
  __syncthreads();
  if (threadIdx.x==0) *flag = (cnt==0)?4:1;   // 4: int32 mask (LSB), 1: bool/uint8
}

// ---------------- mask bit-pack: 16 elements per thread -> u16 word ----------------
__global__ __launch_bounds__(256) void pack_mask_kernel(const unsigned char* __restrict__ m,
    const int* __restrict__ flag, u16* __restrict__ mb16){
  const int stride = *flag;
  const size_t gid = (size_t)blockIdx.x*256u + threadIdx.x;   // 1,048,576 threads
  u32 bits = 0;
  if (stride == 1){
    const uint4 v = *(const uint4*)(m + gid*16);
    bits  =  ((v.x & 0x01010101u) * 0x01020408u) >> 24;
    bits |= (((v.y & 0x01010101u) * 0x01020408u) >> 24) << 4;
    bits |= (((v.z & 0x01010101u) * 0x01020408u) >> 24) << 8;
    bits |= (((v.w & 0x01010101u) * 0x01020408u) >> 24) << 12;
  } else {
    const unsigned char* mm = m + gid*64;
    const uint4 a = *(const uint4*)(mm);
    const uint4 b = *(const uint4*)(mm+16);
    const uint4 c = *(const uint4*)(mm+32);
    const uint4 d = *(const uint4*)(mm+48);
    bits  = (u32)(a.x!=0) | ((u32)(a.y!=0)<<1) | ((u32)(a.z!=0)<<2) | ((u32)(a.w!=0)<<3)
          | ((u32)(b.x!=0)<<4) | ((u32)(b.y!=0)<<5) | ((u32)(b.z!=0)<<6) | ((u32)(b.w!=0)<<7)
          | ((u32)(c.x!=0)<<8) | ((u32)(c.y!=0)<<9) | ((u32)(c.z!=0)<<10)| ((u32)(c.w!=0)<<11)
          | ((u32)(d.x!=0)<<12)| ((u32)(d.y!=0)<<13)| ((u32)(d.z!=0)<<14)| ((u32)(d.w!=0)<<15);
  }
  mb16[gid] = (u16)bits;
}

// ---------------- weight prep: bf16 + [n][k] transpose; Wq pre-scaled by 0.125*log2(e) ----------------
__global__ __launch_bounds__(256) void prep_weights_kernel(
    const float* __restrict__ Wq, const float* __restrict__ Wk, const float* __restrict__ Wv,
    const float* __restrict__ Wo, u16* __restrict__ WT, u16* __restrict__ WoT){
  int gid = blockIdx.x*256 + threadIdx.x;
  if (gid < 3*512*1024){
    int z = gid >> 19;
    int r = gid & ((1<<19)-1);
    int n = r >> 10, d = r & 1023;
    const float* W = (z==0)?Wq:((z==1)?Wk:Wv);
    int h = n>>5, e = n&31;
    float wv = W[((size_t)h*1024 + (size_t)d)*32 + e];
    if (z==0) wv *= 0.18033688011112042f;   // (1/sqrt(64)) * log2(e)
    WT[gid] = f2bf(wv);
  } else {
    int r = gid - 3*512*1024;
    int n = r >> 9, cc = r & 511;
    WoT[r] = f2bf(Wo[(size_t)cc*1024 + n]);
  }
}

// ---------------- projection GEMM: [8192x1024]f32 x WT[n][k] -> Q/K (bf16 [B,H,S,32]) or V^T (bf16 [B,H,32,S])
__global__ __launch_bounds__(256) void gemm_proj_kernel(
    const float* __restrict__ Aq, const float* __restrict__ Ak, const float* __restrict__ Av,
    const u16* __restrict__ WT, u16* __restrict__ Qp, u16* __restrict__ Kp, u16* __restrict__ Vt)
{
  __shared__ u16 As[128*64];
  __shared__ u16 Bs[128*64];
  const int z = blockIdx.z;
  const float* __restrict__ A = (z==0)?Aq:((z==1)?Ak:Av);
  const u16* __restrict__ W = WT + (size_t)z*(512*1024);
  const int m0 = blockIdx.x*128, n0 = blockIdx.y*128;
  const int t = threadIdx.x, lane = t&63, wv = t>>6;
  const int wr = wv>>1, wc = wv&1;
  const int c = lane&15, g = lane>>4;
  f32x4 acc[4][4] = {};
  for (int kk=0; kk<1024; kk+=64){
    #pragma unroll
    for (int j=0;j<8;j++){                       // A: 128x64 f32 -> bf16 LDS (swizzled), cvt_pk packing
      int idx = t + j*256;
      int row = idx>>4, kq=(idx&15)<<2;
      f32x4 a4 = *(const f32x4*)(A + (size_t)(m0+row)*1024 + kk + kq);
      u32x2 w2;
      w2[0] = cvt_pk_bf16(a4[0], a4[1]);
      w2[1] = cvt_pk_bf16(a4[2], a4[3]);
      int co = (kq<<1) ^ ((row&7)<<4);
      *(u32x2*)((char*)As + row*128 + co) = w2;
    }
    #pragma unroll
    for (int j=0;j<4;j++){                       // B: 128x64 bf16
      int idx = t + j*256;
      int n = idx>>3, k8=(idx&7)<<3;
      s16x8 bv = *(const s16x8*)(W + (size_t)(n0+n)*1024 + kk + k8);
      int co = (k8<<1) ^ ((n&7)<<4);
      *(s16x8*)((char*)Bs + n*128 + co) = bv;
    }
    __syncthreads();
    #pragma unroll
    for (int ks=0;ks<2;ks++){
      s16x8 af[4], bf[4];
      #pragma unroll
      for (int i=0;i<4;i++){
        int ra = wr*64 + i*16 + c;
        af[i] = *(const s16x8*)((const char*)As + ra*128 + ((ks*64 + g*16) ^ ((ra&7)<<4)));
        int rb = wc*64 + i*16 + c;
        bf[i] = *(const s16x8*)((const char*)Bs + rb*128 + ((ks*64 + g*16) ^ ((rb&7)<<4)));
      }
      #pragma unroll
      for (int mi=0;mi<4;mi++)
        #pragma unroll
        for (int nj=0;nj<4;nj++)
          acc[mi][nj] = __builtin_amdgcn_mfma_f32_16x16x32_bf16(af[mi], bf[nj], acc[mi][nj], 0, 0, 0);
    }
    __syncthreads();
  }
  #pragma unroll
  for (int mi=0;mi<4;mi++){
    #pragma unroll
    for (int nj=0;nj<4;nj++){
      #pragma unroll
      for (int r=0;r<4;r++){
        int gm = m0 + wr*64 + mi*16 + g*4 + r;
        int gn = n0 + wc*64 + nj*16 + c;
        u16 val = f2bf(acc[mi][nj][r]);
        int b = gm>>11, s = gm&2047, hh = gn>>5, e = gn&31;
        if (z==0)      Qp[((size_t)(b*16+hh)*2048 + s)*32 + e] = val;
        else if (z==1) Kp[((size_t)(b*16+hh)*2048 + s)*32 + e] = val;
        else           Vt[((size_t)(b*16+hh)*32 + e)*2048 + s] = val;
      }
    }
  }
}

// ---------------- flash attention: swapped 32x32, no-max exp2 softmax, even/odd dual chains (R7 exact) ------
// No running max -> partial sums over disjoint K ranges are exactly additive. Each iteration
// processes TWO k-tiles as fully independent chains (separate p, separate O/L accumulators),
// giving 2x chain-level ILP inside a wave; merged in the epilogue.
__global__ __launch_bounds__(256, 4) void attn_kernel(
    const u16* __restrict__ Qp, const u16* __restrict__ Kp, const u16* __restrict__ Vt,
    const u32* __restrict__ mb32, u16* __restrict__ Z)
{
  __shared__ float Osh[4][32][36];
  const int t = threadIdx.x, lane = t&63, wid = t>>6;
  const int c = lane&31, hi = lane>>5;
  const int hi8 = hi*8;
  // XCD-aware swizzle: all 16 q-tiles of one bh land on one XCD
  const int wg = blockIdx.x;            // 0..1023
  const int xcd = wg & 7, loc = wg >> 3;
  const int bh = xcd*8 + (loc>>4);
  const int qb = loc & 15;
  const int b = bh>>4, h = bh&15;
  const int q0 = qb*128 + wid*32;
  const u16* Qh = Qp + (size_t)bh*2048*32;
  const u16* Kh = Kp + (size_t)bh*2048*32;
  const u16* Vh = Vt + (size_t)bh*32*2048;

  // Q B-frag: col=q=c, k-dim = hd  (Q pre-scaled by 0.125*log2e)
  const s16x8 qf0 = *(const s16x8*)(Qh + (size_t)(q0 + c)*32 + hi8);
  const s16x8 qf1 = *(const s16x8*)(Qh + (size_t)(q0 + c)*32 + 16 + hi8);

  const f32x16 z16 = {0,0,0,0,0,0,0,0,0,0,0,0,0,0,0,0};
  f32x16 OA = z16, OB = z16;
  f32x4 LA = {0,0,0,0}, LB = {0,0,0,0};
  const u32* mrowp = mb32 + ((size_t)b*2048 + (size_t)(q0 + c))*64;  // 64 u32 words per q-row

  for (int kt = 0; kt < 64; kt += 2){
    const int kbA = kt*32, kbB = kbA + 32;
    // ---- loads for both chains (independent) ----
    const u16* kbaseA = Kh + (size_t)(kbA + c)*32 + hi8;
    const s16x8 kfA0 = *(const s16x8*)(kbaseA);
    const s16x8 kfA1 = *(const s16x8*)(kbaseA + 16);
    const u16* kbaseB = Kh + (size_t)(kbB + c)*32 + hi8;
    const s16x8 kfB0 = *(const s16x8*)(kbaseB);
    const s16x8 kfB1 = *(const s16x8*)(kbaseB + 16);
    const u16* vbase = Vh + (size_t)c*2048 + kbA + hi8;
    const s16x8 vfA0 = *(const s16x8*)(vbase);
    const s16x8 vfA1 = *(const s16x8*)(vbase + 16);
    const s16x8 vfB0 = *(const s16x8*)(vbase + 32);
    const s16x8 vfB1 = *(const s16x8*)(vbase + 48);
    const u64 mw = *(const u64*)(mrowp + kt);
    const u32 msnA = ~(((u32)mw) >> (4*hi));
    const u32 msnB = ~(((u32)(mw >> 32)) >> (4*hi));

    // ---- QK^T (swapped): independent accumulator chains ----
    f32x16 pA = __builtin_amdgcn_mfma_f32_32x32x16_bf16(kfA0, qf0, z16, 0, 0, 0);
    pA = __builtin_amdgcn_mfma_f32_32x32x16_bf16(kfA1, qf1, pA, 0, 0, 0);
    f32x16 pB = __builtin_amdgcn_mfma_f32_32x32x16_bf16(kfB0, qf0, z16, 0, 0, 0);
    pB = __builtin_amdgcn_mfma_f32_32x32x16_bf16(kfB1, qf1, pB, 0, 0, 0);

    // p = exp2(s); zero masked (bit of msn==0 -> masked -> 0)
    #define MZE(P,R,MS) P[R] = mzero<(((R)&3)+8*((R)>>2))>(__builtin_amdgcn_exp2f(P[R]), MS)
    MZE(pA,0,msnA);  MZE(pA,1,msnA);  MZE(pA,2,msnA);  MZE(pA,3,msnA);
    MZE(pA,4,msnA);  MZE(pA,5,msnA);  MZE(pA,6,msnA);  MZE(pA,7,msnA);
    MZE(pA,8,msnA);  MZE(pA,9,msnA);  MZE(pA,10,msnA); MZE(pA,11,msnA);
    MZE(pA,12,msnA); MZE(pA,13,msnA); MZE(pA,14,msnA); MZE(pA,15,msnA);
    MZE(pB,0,msnB);  MZE(pB,1,msnB);  MZE(pB,2,msnB);  MZE(pB,3,msnB);
    MZE(pB,4,msnB);  MZE(pB,5,msnB);  MZE(pB,6,msnB);  MZE(pB,7,msnB);
    MZE(pB,8,msnB);  MZE(pB,9,msnB);  MZE(pB,10,msnB); MZE(pB,11,msnB);
    MZE(pB,12,msnB); MZE(pB,13,msnB); MZE(pB,14,msnB); MZE(pB,15,msnB);
    #undef MZE

    // ---- l partial sums via VALU (off critical path, 4 accumulators per chain) ----
    #pragma unroll
    for (int i=0;i<4;i++){
      LA[i] += (pA[i] + pA[i+4]) + (pA[i+8] + pA[i+12]);
      LB[i] += (pB[i] + pB[i+4]) + (pB[i+8] + pB[i+12]);
    }

    // ---- P^T B-frags: cvt_pk pairs + permlane swaps (wiring verified R3/R4) ----
    u32 pwA0 = cvt_pk_bf16(pA[0],  pA[1]);
    u32 pwA1 = cvt_pk_bf16(pA[2],  pA[3]);
    u32 pwA2 = cvt_pk_bf16(pA[4],  pA[5]);
    u32 pwA3 = cvt_pk_bf16(pA[6],  pA[7]);
    u32 pwA4 = cvt_pk_bf16(pA[8],  pA[9]);
    u32 pwA5 = cvt_pk_bf16(pA[10], pA[11]);
    u32 pwA6 = cvt_pk_bf16(pA[12], pA[13]);
    u32 pwA7 = cvt_pk_bf16(pA[14], pA[15]);
    u32x2 a02 = pl32swap(pwA0, pwA2);
    u32x2 a13 = pl32swap(pwA1, pwA3);
    u32x2 a46 = pl32swap(pwA4, pwA6);
    u32x2 a57 = pl32swap(pwA5, pwA7);
    union { u32 u[4]; s16x8 v; } fA0 = {{a02[0], a13[0], a02[1], a13[1]}};
    union { u32 u[4]; s16x8 v; } fA1 = {{a46[0], a57[0], a46[1], a57[1]}};
    u32 pwB0 = cvt_pk_bf16(pB[0],  pB[1]);
    u32 pwB1 = cvt_pk_bf16(pB[2],  pB[3]);
    u32 pwB2 = cvt_pk_bf16(pB[4],  pB[5]);
    u32 pwB3 = cvt_pk_bf16(pB[6],  pB[7]);
    u32 pwB4 = cvt_pk_bf16(pB[8],  pB[9]);
    u32 pwB5 = cvt_pk_bf16(pB[10], pB[11]);
    u32 pwB6 = cvt_pk_bf16(pB[12], pB[13]);
    u32 pwB7 = cvt_pk_bf16(pB[14], pB[15]);
    u32x2 b02 = pl32swap(pwB0, pwB2);
    u32x2 b13 = pl32swap(pwB1, pwB3);
    u32x2 b46 = pl32swap(pwB4, pwB6);
    u32x2 b57 = pl32swap(pwB5, pwB7);
    union { u32 u[4]; s16x8 v; } fB0 = {{b02[0], b13[0], b02[1], b13[1]}};
    union { u32 u[4]; s16x8 v; } fB1 = {{b46[0], b57[0], b46[1], b57[1]}};

    // ---- PV: independent accumulators ----
    OA = __builtin_amdgcn_mfma_f32_32x32x16_bf16(vfA0, fA0.v, OA, 0, 0, 0);
    OA = __builtin_amdgcn_mfma_f32_32x32x16_bf16(vfA1, fA1.v, OA, 0, 0, 0);
    OB = __builtin_amdgcn_mfma_f32_32x32x16_bf16(vfB0, fB0.v, OB, 0, 0, 0);
    OB = __builtin_amdgcn_mfma_f32_32x32x16_bf16(vfB1, fB1.v, OB, 0, 0, 0);
  }

  // epilogue: merge chains, total l, normalize, transpose via LDS, store
  const float lown = ((LA[0]+LB[0]) + (LA[1]+LB[1])) + ((LA[2]+LB[2]) + (LA[3]+LB[3]));
  const float linv = 1.0f / xhalf_sum(lown);
  #pragma unroll
  for (int r=0;r<16;r++){
    const int hd = (r&3) + 8*(r>>2) + 4*hi;
    Osh[wid][c][hd] = (OA[r] + OB[r]) * linv;
  }
  __syncthreads();
  const int rq = lane >> 1, rc0 = (lane & 1)*16;
  const float* orow = &Osh[wid][rq][0];
  union { u16 q[8]; s16x8 v; } o0, o1;
  #pragma unroll
  for (int j=0;j<8;j++){ o0.q[j] = f2bf(orow[rc0+j]); o1.q[j] = f2bf(orow[rc0+8+j]); }
  u16* zp = Z + ((size_t)b*2048 + (size_t)(q0 + rq))*512 + h*32 + rc0;
  *(s16x8*)(zp)   = o0.v;
  *(s16x8*)(zp+8) = o1.v;
}

// ---------------- output GEMM: Z[8192x512]bf16 x WoT[1024][512] -> out f32 ----------------
__global__ __launch_bounds__(256) void gemm_out_kernel(
    const u16* __restrict__ Zb, const u16* __restrict__ WoT, float* __restrict__ out)
{
  __shared__ u16 As[128*64];
  __shared__ u16 Bs[128*64];
  const int m0 = blockIdx.x*128, n0 = blockIdx.y*128;
  const int t = threadIdx.x, lane=t&63, wv=t>>6;
  const int wr=wv>>1, wc=wv&1, c=lane&15, g=lane>>4;
  f32x4 acc[4][4] = {};
  for (int kk=0; kk<512; kk+=64){
    #pragma unroll
    for (int j=0;j<4;j++){
      int idx = t + j*256;
      int row = idx>>3, k8=(idx&7)<<3;
      int co = (k8<<1) ^ ((row&7)<<4);
      s16x8 av = *(const s16x8*)(Zb + (size_t)(m0+row)*512 + kk + k8);
      *(s16x8*)((char*)As + row*128 + co) = av;
      s16x8 bv = *(const s16x8*)(WoT + (size_t)(n0+row)*512 + kk + k8);
      *(s16x8*)((char*)Bs + row*128 + co) = bv;
    }
    __syncthreads();
    #pragma unroll
    for (int ks=0;ks<2;ks++){
      s16x8 af[4], bf[4];
      #pragma unroll
      for (int i=0;i<4;i++){
        int ra = wr*64 + i*16 + c;
        af[i] = *(const s16x8*)((const char*)As + ra*128 + ((ks*64 + g*16) ^ ((ra&7)<<4)));
        int rb = wc*64 + i*16 + c;
        bf[i] = *(const s16x8*)((const char*)Bs + rb*128 + ((ks*64 + g*16) ^ ((rb&7)<<4)));
      }
      #pragma unroll
      for (int mi=0;mi<4;mi++)
        #pragma unroll
        for (int nj=0;nj<4;nj++)
          acc[mi][nj] = __builtin_amdgcn_mfma_f32_16x16x32_bf16(af[mi], bf[nj], acc[mi][nj], 0, 0, 0);
    }
    __syncthreads();
  }
  #pragma unroll
  for (int mi=0;mi<4;mi++)
    #pragma unroll
    for (int nj=0;nj<4;nj++)
      #pragma unroll
      for (int r=0;r<4;r++){
        int gm = m0 + wr*64 + mi*16 + g*4 + r;
        int gn = n0 + wc*64 + nj*16 + c;
        out[(size_t)gm*1024 + gn] = acc[mi][nj][r];
      }
}

// ---------------- launcher ----------------
extern "C" void kernel_launch(void* const* d_in, const int* in_sizes, int n_in,
                              void* d_out, int out_size, void* d_ws, size_t ws_size,
                              hipStream_t stream)
{
  const float* q  = (const float*)d_in[0];
  const float* k  = (const float*)d_in[1];
  const float* v  = (const float*)d_in[2];
  const unsigned char* mask = (const unsigned char*)d_in[3];
  const float* Wq = (const float*)d_in[4];
  const float* Wk = (const float*)d_in[5];
  const float* Wv = (const float*)d_in[6];
  const float* Wo = (const float*)d_in[7];
  float* out = (float*)d_out;

  char* ws = (char*)d_ws;
  u16* Qp  = (u16*)(ws);                         //  8,388,608 B  [B,H,S,32] bf16
  u16* Kp  = (u16*)(ws + 8388608);               //  8,388,608 B
  u16* Vt  = (u16*)(ws + 16777216);              //  8,388,608 B  [B,H,32,S] bf16
  u16* Z   = (u16*)(ws + 25165824);              //  8,388,608 B  [B*S, 512] bf16
  u16* WT  = (u16*)(ws + 33554432);              //  3,145,728 B  [3][512][1024] bf16
  u16* WoT = (u16*)(ws + 36700160);              //  1,048,576 B  [1024][512] bf16
  u16* mb16 = (u16*)(ws + 37748736);             //  2,097,152 B  mask bits
  int* flag = (int*)(ws + 39845888);

  detect_mask_kernel<<<1, 256, 0, stream>>>(mask, flag);
  pack_mask_kernel<<<4096, 256, 0, stream>>>(mask, flag, mb16);
  prep_weights_kernel<<<8192, 256, 0, stream>>>(Wq, Wk, Wv, Wo, WT, WoT);
  gemm_proj_kernel<<<dim3(64,4,3), 256, 0, stream>>>(q, k, v, WT, Qp, Kp, Vt);
  attn_kernel<<<1024, 256, 0, stream>>>(Qp, Kp, Vt, (const u32*)mb16, Z);
  gemm_out_kernel<<<dim3(64,8), 256, 0, stream>>>(Z, WoT, out);
  (void)in_sizes; (void)n_in; (void)out_size; (void)ws_size;
}

// Round 14
// 204.484 us; speedup vs baseline: 2.4200x; 1.0126x over previous
//
#include <hip/hip_runtime.h>
#include <hip/hip_bf16.h>
#include <math.h>

// B=4, S=2048, D_MODEL=1024, H=16, HD=32, SCALE=8.0
typedef unsigned short u16;
typedef unsigned int u32;
typedef unsigned long long u64;
typedef __attribute__((ext_vector_type(8))) short s16x8;
typedef __attribute__((ext_vector_type(4))) short s16x4;
typedef __attribute__((ext_vector_type(4))) float f32x4;
typedef __attribute__((ext_vector_type(16))) float f32x16;
typedef __attribute__((ext_vector_type(2))) unsigned int u32x2;

#define DEV static __device__ __forceinline__

DEV u16 f2bf(float f){
  __hip_bfloat16 h = __float2bfloat16(f);
  return *reinterpret_cast<u16*>(&h);
}

DEV u32 cvt_pk_bf16(float lo, float hi_){
  u32 r;
  asm("v_cvt_pk_bf16_f32 %0, %1, %2" : "=v"(r) : "v"(lo), "v"(hi_));
  return r;  // low16 = bf16(lo), high16 = bf16(hi_)
}

// SSA-clean permlane32 swap: returns {a.lo||b.lo, a.hi||b.hi} (verified R3->R4 pass)
DEV u32x2 pl32swap(u32 a, u32 b){
  return __builtin_amdgcn_permlane32_swap(a, b, false, false);
}
DEV float xhalf_sum(float x){
  u32x2 r = pl32swap(__float_as_uint(x), __float_as_uint(x));
  return __uint_as_float(r[0]) + __uint_as_float(r[1]);
}

// masked-zero: ext = sext(bit CPOS of msn) (msn = ~mask, so unmasked -> -1 keep, masked -> 0)
template<int CPOS> DEV float mzero(float p, u32 msn){
  int ext;
  asm("v_bfe_i32 %0, %1, %2, 1" : "=v"(ext) : "v"(msn), "n"(CPOS));
  return __uint_as_float(__float_as_uint(p) & (u32)ext);
}

// async global->LDS, 16B per lane; LDS dest = wave-uniform base + lane*16, global src per-lane
// (correctness verified on-device in R12)
DEV void gload16(const u16* g, u16* l){
  __builtin_amdgcn_global_load_lds((const __attribute__((address_space(1))) void*)g,
                                   (__attribute__((address_space(3))) void*)l, 16, 0, 0);
}

// ---------------- mask dtype detect ----------------
__global__ void detect_mask_kernel(const unsigned char* __restrict__ m, int* __restrict__ flag){
  __shared__ int cnt;
  if (threadIdx.x==0) cnt=0;
  __syncthreads();
  int nz=0;
  for (int i=threadIdx.x;i<4096;i+=256) nz += (m[(size_t)i*4+1]!=0)?1:0;
  if (nz) atomicAdd(&cnt, nz);
  __syncthreads();
  if (threadIdx.x==0) *flag = (cnt==0)?4:1;   // 4: int32 mask (LSB), 1: bool/uint8
}

// ---------------- mask bit-pack: 16 elements per thread -> u16 word ----------------
__global__ __launch_bounds__(256) void pack_mask_kernel(const unsigned char* __restrict__ m,
    const int* __restrict__ flag, u16* __restrict__ mb16){
  const int stride = *flag;
  const size_t gid = (size_t)blockIdx.x*256u + threadIdx.x;   // 1,048,576 threads
  u32 bits = 0;
  if (stride == 1){
    const uint4 v = *(const uint4*)(m + gid*16);
    bits  =  ((v.x & 0x01010101u) * 0x01020408u) >> 24;
    bits |= (((v.y & 0x01010101u) * 0x01020408u) >> 24) << 4;
    bits |= (((v.z & 0x01010101u) * 0x01020408u) >> 24) << 8;
    bits |= (((v.w & 0x01010101u) * 0x01020408u) >> 24) << 12;
  } else {
    const unsigned char* mm = m + gid*64;
    const uint4 a = *(const uint4*)(mm);
    const uint4 b = *(const uint4*)(mm+16);
    const uint4 c = *(const uint4*)(mm+32);
    const uint4 d = *(const uint4*)(mm+48);
    bits  = (u32)(a.x!=0) | ((u32)(a.y!=0)<<1) | ((u32)(a.z!=0)<<2) | ((u32)(a.w!=0)<<3)
          | ((u32)(b.x!=0)<<4) | ((u32)(b.y!=0)<<5) | ((u32)(b.z!=0)<<6) | ((u32)(b.w!=0)<<7)
          | ((u32)(c.x!=0)<<8) | ((u32)(c.y!=0)<<9) | ((u32)(c.z!=0)<<10)| ((u32)(c.w!=0)<<11)
          | ((u32)(d.x!=0)<<12)| ((u32)(d.y!=0)<<13)| ((u32)(d.z!=0)<<14)| ((u32)(d.w!=0)<<15);
  }
  mb16[gid] = (u16)bits;
}

// ---------------- weight prep: bf16 + [n][k] transpose; Wq pre-scaled by 0.125*log2(e) ----------------
__global__ __launch_bounds__(256) void prep_weights_kernel(
    const float* __restrict__ Wq, const float* __restrict__ Wk, const float* __restrict__ Wv,
    const float* __restrict__ Wo, u16* __restrict__ WT, u16* __restrict__ WoT){
  int gid = blockIdx.x*256 + threadIdx.x;
  if (gid < 3*512*1024){
    int z = gid >> 19;
    int r = gid & ((1<<19)-1);
    int n = r >> 10, d = r & 1023;
    const float* W = (z==0)?Wq:((z==1)?Wk:Wv);
    int h = n>>5, e = n&31;
    float wv = W[((size_t)h*1024 + (size_t)d)*32 + e];
    if (z==0) wv *= 0.18033688011112042f;   // (1/sqrt(64)) * log2(e)
    WT[gid] = f2bf(wv);
  } else {
    int r = gid - 3*512*1024;
    int n = r >> 9, cc = r & 511;
    WoT[r] = f2bf(Wo[(size_t)cc*1024 + n]);
  }
}

// ---------------- projection GEMM: [8192x1024]f32 x WT[n][k] -> Q/K (bf16 [B,H,S,32]) or V^T (bf16 [B,H,32,S])
// B staged via global_load_lds with inverse-swizzled per-lane global source (linear LDS dest).
__global__ __launch_bounds__(256) void gemm_proj_kernel(
    const float* __restrict__ Aq, const float* __restrict__ Ak, const float* __restrict__ Av,
    const u16* __restrict__ WT, u16* __restrict__ Qp, u16* __restrict__ Kp, u16* __restrict__ Vt)
{
  __shared__ u16 As[128*64];
  __shared__ u16 Bs[128*64];
  const int z = blockIdx.z;
  const float* __restrict__ A = (z==0)?Aq:((z==1)?Ak:Av);
  const u16* __restrict__ W = WT + (size_t)z*(512*1024);
  const int m0 = blockIdx.x*128, n0 = blockIdx.y*128;
  const int t = threadIdx.x, lane = t&63, wv = t>>6;
  const int wr = wv>>1, wc = wv&1;
  const int c = lane&15, g = lane>>4;
  f32x4 acc[4][4] = {};
  for (int kk=0; kk<1024; kk+=64){
    // B: global_load_lds, linear LDS dest, source pre-swizzled so reads keep the XOR layout
    #pragma unroll
    for (int j=0;j<4;j++){
      const int chunk = j*4 + wv;                 // 16 x 1KB chunks
      const int idx2 = chunk*64 + lane;           // 0..1023
      const int n = idx2>>3, cb = (idx2&7)<<4;    // dest row, dest 16B block
      const int koff = (cb ^ ((n&7)<<4)) >> 1;    // source element offset within row
      gload16(W + (size_t)(n0+n)*1024 + kk + koff, (u16*)((char*)Bs + chunk*1024));
    }
    #pragma unroll
    for (int j=0;j<8;j++){                       // A: 128x64 f32 -> bf16 LDS (swizzled), cvt_pk packing
      int idx = t + j*256;
      int row = idx>>4, kq=(idx&15)<<2;
      f32x4 a4 = *(const f32x4*)(A + (size_t)(m0+row)*1024 + kk + kq);
      u32x2 w2;
      w2[0] = cvt_pk_bf16(a4[0], a4[1]);
      w2[1] = cvt_pk_bf16(a4[2], a4[3]);
      int co = (kq<<1) ^ ((row&7)<<4);
      *(u32x2*)((char*)As + row*128 + co) = w2;
    }
    __syncthreads();
    #pragma unroll
    for (int ks=0;ks<2;ks++){
      s16x8 af[4], bf[4];
      #pragma unroll
      for (int i=0;i<4;i++){
        int ra = wr*64 + i*16 + c;
        af[i] = *(const s16x8*)((const char*)As + ra*128 + ((ks*64 + g*16) ^ ((ra&7)<<4)));
        int rb = wc*64 + i*16 + c;
        bf[i] = *(const s16x8*)((const char*)Bs + rb*128 + ((ks*64 + g*16) ^ ((rb&7)<<4)));
      }
      #pragma unroll
      for (int mi=0;mi<4;mi++)
        #pragma unroll
        for (int nj=0;nj<4;nj++)
          acc[mi][nj] = __builtin_amdgcn_mfma_f32_16x16x32_bf16(af[mi], bf[nj], acc[mi][nj], 0, 0, 0);
    }
    __syncthreads();
  }
  #pragma unroll
  for (int mi=0;mi<4;mi++){
    #pragma unroll
    for (int nj=0;nj<4;nj++){
      #pragma unroll
      for (int r=0;r<4;r++){
        int gm = m0 + wr*64 + mi*16 + g*4 + r;
        int gn = n0 + wc*64 + nj*16 + c;
        u16 val = f2bf(acc[mi][nj][r]);
        int b = gm>>11, s = gm&2047, hh = gn>>5, e = gn&31;
        if (z==0)      Qp[((size_t)(b*16+hh)*2048 + s)*32 + e] = val;
        else if (z==1) Kp[((size_t)(b*16+hh)*2048 + s)*32 + e] = val;
        else           Vt[((size_t)(b*16+hh)*32 + e)*2048 + s] = val;
      }
    }
  }
}

// ---------------- flash attention: swapped 32x32, no-max exp2 softmax, even/odd dual chains (R7/R13 exact) ----
__global__ __launch_bounds__(256, 4) void attn_kernel(
    const u16* __restrict__ Qp, const u16* __restrict__ Kp, const u16* __restrict__ Vt,
    const u32* __restrict__ mb32, u16* __restrict__ Z)
{
  __shared__ float Osh[4][32][36];
  const int t = threadIdx.x, lane = t&63, wid = t>>6;
  const int c = lane&31, hi = lane>>5;
  const int hi8 = hi*8;
  // XCD-aware swizzle: all 16 q-tiles of one bh land on one XCD
  const int wg = blockIdx.x;            // 0..1023
  const int xcd = wg & 7, loc = wg >> 3;
  const int bh = xcd*8 + (loc>>4);
  const int qb = loc & 15;
  const int b = bh>>4, h = bh&15;
  const int q0 = qb*128 + wid*32;
  const u16* Qh = Qp + (size_t)bh*2048*32;
  const u16* Kh = Kp + (size_t)bh*2048*32;
  const u16* Vh = Vt + (size_t)bh*32*2048;

  // Q B-frag: col=q=c, k-dim = hd  (Q pre-scaled by 0.125*log2e)
  const s16x8 qf0 = *(const s16x8*)(Qh + (size_t)(q0 + c)*32 + hi8);
  const s16x8 qf1 = *(const s16x8*)(Qh + (size_t)(q0 + c)*32 + 16 + hi8);

  const f32x16 z16 = {0,0,0,0,0,0,0,0,0,0,0,0,0,0,0,0};
  f32x16 OA = z16, OB = z16;
  f32x4 LA = {0,0,0,0}, LB = {0,0,0,0};
  const u32* mrowp = mb32 + ((size_t)b*2048 + (size_t)(q0 + c))*64;  // 64 u32 words per q-row

  for (int kt = 0; kt < 64; kt += 2){
    const int kbA = kt*32, kbB = kbA + 32;
    // ---- loads for both chains (independent) ----
    const u16* kbaseA = Kh + (size_t)(kbA + c)*32 + hi8;
    const s16x8 kfA0 = *(const s16x8*)(kbaseA);
    const s16x8 kfA1 = *(const s16x8*)(kbaseA + 16);
    const u16* kbaseB = Kh + (size_t)(kbB + c)*32 + hi8;
    const s16x8 kfB0 = *(const s16x8*)(kbaseB);
    const s16x8 kfB1 = *(const s16x8*)(kbaseB + 16);
    const u16* vbase = Vh + (size_t)c*2048 + kbA + hi8;
    const s16x8 vfA0 = *(const s16x8*)(vbase);
    const s16x8 vfA1 = *(const s16x8*)(vbase + 16);
    const s16x8 vfB0 = *(const s16x8*)(vbase + 32);
    const s16x8 vfB1 = *(const s16x8*)(vbase + 48);
    const u64 mw = *(const u64*)(mrowp + kt);
    const u32 msnA = ~(((u32)mw) >> (4*hi));
    const u32 msnB = ~(((u32)(mw >> 32)) >> (4*hi));

    // ---- QK^T (swapped): independent accumulator chains ----
    f32x16 pA = __builtin_amdgcn_mfma_f32_32x32x16_bf16(kfA0, qf0, z16, 0, 0, 0);
    pA = __builtin_amdgcn_mfma_f32_32x32x16_bf16(kfA1, qf1, pA, 0, 0, 0);
    f32x16 pB = __builtin_amdgcn_mfma_f32_32x32x16_bf16(kfB0, qf0, z16, 0, 0, 0);
    pB = __builtin_amdgcn_mfma_f32_32x32x16_bf16(kfB1, qf1, pB, 0, 0, 0);

    // p = exp2(s); zero masked (bit of msn==0 -> masked -> 0)
    #define MZE(P,R,MS) P[R] = mzero<(((R)&3)+8*((R)>>2))>(__builtin_amdgcn_exp2f(P[R]), MS)
    MZE(pA,0,msnA);  MZE(pA,1,msnA);  MZE(pA,2,msnA);  MZE(pA,3,msnA);
    MZE(pA,4,msnA);  MZE(pA,5,msnA);  MZE(pA,6,msnA);  MZE(pA,7,msnA);
    MZE(pA,8,msnA);  MZE(pA,9,msnA);  MZE(pA,10,msnA); MZE(pA,11,msnA);
    MZE(pA,12,msnA); MZE(pA,13,msnA); MZE(pA,14,msnA); MZE(pA,15,msnA);
    MZE(pB,0,msnB);  MZE(pB,1,msnB);  MZE(pB,2,msnB);  MZE(pB,3,msnB);
    MZE(pB,4,msnB);  MZE(pB,5,msnB);  MZE(pB,6,msnB);  MZE(pB,7,msnB);
    MZE(pB,8,msnB);  MZE(pB,9,msnB);  MZE(pB,10,msnB); MZE(pB,11,msnB);
    MZE(pB,12,msnB); MZE(pB,13,msnB); MZE(pB,14,msnB); MZE(pB,15,msnB);
    #undef MZE

    // ---- l partial sums via VALU (off critical path, 4 accumulators per chain) ----
    #pragma unroll
    for (int i=0;i<4;i++){
      LA[i] += (pA[i] + pA[i+4]) + (pA[i+8] + pA[i+12]);
      LB[i] += (pB[i] + pB[i+4]) + (pB[i+8] + pB[i+12]);
    }

    // ---- P^T B-frags: cvt_pk pairs + permlane swaps (wiring verified R3/R4) ----
    u32 pwA0 = cvt_pk_bf16(pA[0],  pA[1]);
    u32 pwA1 = cvt_pk_bf16(pA[2],  pA[3]);
    u32 pwA2 = cvt_pk_bf16(pA[4],  pA[5]);
    u32 pwA3 = cvt_pk_bf16(pA[6],  pA[7]);
    u32 pwA4 = cvt_pk_bf16(pA[8],  pA[9]);
    u32 pwA5 = cvt_pk_bf16(pA[10], pA[11]);
    u32 pwA6 = cvt_pk_bf16(pA[12], pA[13]);
    u32 pwA7 = cvt_pk_bf16(pA[14], pA[15]);
    u32x2 a02 = pl32swap(pwA0, pwA2);
    u32x2 a13 = pl32swap(pwA1, pwA3);
    u32x2 a46 = pl32swap(pwA4, pwA6);
    u32x2 a57 = pl32swap(pwA5, pwA7);
    union { u32 u[4]; s16x8 v; } fA0 = {{a02[0], a13[0], a02[1], a13[1]}};
    union { u32 u[4]; s16x8 v; } fA1 = {{a46[0], a57[0], a46[1], a57[1]}};
    u32 pwB0 = cvt_pk_bf16(pB[0],  pB[1]);
    u32 pwB1 = cvt_pk_bf16(pB[2],  pB[3]);
    u32 pwB2 = cvt_pk_bf16(pB[4],  pB[5]);
    u32 pwB3 = cvt_pk_bf16(pB[6],  pB[7]);
    u32 pwB4 = cvt_pk_bf16(pB[8],  pB[9]);
    u32 pwB5 = cvt_pk_bf16(pB[10], pB[11]);
    u32 pwB6 = cvt_pk_bf16(pB[12], pB[13]);
    u32 pwB7 = cvt_pk_bf16(pB[14], pB[15]);
    u32x2 b02 = pl32swap(pwB0, pwB2);
    u32x2 b13 = pl32swap(pwB1, pwB3);
    u32x2 b46 = pl32swap(pwB4, pwB6);
    u32x2 b57 = pl32swap(pwB5, pwB7);
    union { u32 u[4]; s16x8 v; } fB0 = {{b02[0], b13[0], b02[1], b13[1]}};
    union { u32 u[4]; s16x8 v; } fB1 = {{b46[0], b57[0], b46[1], b57[1]}};

    // ---- PV: independent accumulators ----
    OA = __builtin_amdgcn_mfma_f32_32x32x16_bf16(vfA0, fA0.v, OA, 0, 0, 0);
    OA = __builtin_amdgcn_mfma_f32_32x32x16_bf16(vfA1, fA1.v, OA, 0, 0, 0);
    OB = __builtin_amdgcn_mfma_f32_32x32x16_bf16(vfB0, fB0.v, OB, 0, 0, 0);
    OB = __builtin_amdgcn_mfma_f32_32x32x16_bf16(vfB1, fB1.v, OB, 0, 0, 0);
  }

  // epilogue: merge chains, total l, normalize, transpose via LDS, store
  const float lown = ((LA[0]+LB[0]) + (LA[1]+LB[1])) + ((LA[2]+LB[2]) + (LA[3]+LB[3]));
  const float linv = 1.0f / xhalf_sum(lown);
  #pragma unroll
  for (int r=0;r<16;r++){
    const int hd = (r&3) + 8*(r>>2) + 4*hi;
    Osh[wid][c][hd] = (OA[r] + OB[r]) * linv;
  }
  __syncthreads();
  const int rq = lane >> 1, rc0 = (lane & 1)*16;
  const float* orow = &Osh[wid][rq][0];
  union { u16 q[8]; s16x8 v; } o0, o1;
  #pragma unroll
  for (int j=0;j<8;j++){ o0.q[j] = f2bf(orow[rc0+j]); o1.q[j] = f2bf(orow[rc0+8+j]); }
  u16* zp = Z + ((size_t)b*2048 + (size_t)(q0 + rq))*512 + h*32 + rc0;
  *(s16x8*)(zp)   = o0.v;
  *(s16x8*)(zp+8) = o1.v;
}

// ---------------- output GEMM: Z[8192x512]bf16 x WoT[1024][512] -> out f32 ----------------
// Both operands staged via global_load_lds (linear LDS dest, inverse-swizzled global source).
__global__ __launch_bounds__(256) void gemm_out_kernel(
    const u16* __restrict__ Zb, const u16* __restrict__ WoT, float* __restrict__ out)
{
  __shared__ u16 As[128*64];
  __shared__ u16 Bs[128*64];
  const int m0 = blockIdx.x*128, n0 = blockIdx.y*128;
  const int t = threadIdx.x, lane=t&63, wv=t>>6;
  const int wr=wv>>1, wc=wv&1, c=lane&15, g=lane>>4;
  f32x4 acc[4][4] = {};
  for (int kk=0; kk<512; kk+=64){
    #pragma unroll
    for (int j=0;j<4;j++){
      const int chunk = j*4 + wv;                 // 16 x 1KB chunks per tile
      const int idx2 = chunk*64 + lane;           // 0..1023
      const int n = idx2>>3, cb = (idx2&7)<<4;
      const int koff = (cb ^ ((n&7)<<4)) >> 1;
      gload16(Zb  + (size_t)(m0+n)*512 + kk + koff, (u16*)((char*)As + chunk*1024));
      gload16(WoT + (size_t)(n0+n)*512 + kk + koff, (u16*)((char*)Bs + chunk*1024));
    }
    __syncthreads();
    #pragma unroll
    for (int ks=0;ks<2;ks++){
      s16x8 af[4], bf[4];
      #pragma unroll
      for (int i=0;i<4;i++){
        int ra = wr*64 + i*16 + c;
        af[i] = *(const s16x8*)((const char*)As + ra*128 + ((ks*64 + g*16) ^ ((ra&7)<<4)));
        int rb = wc*64 + i*16 + c;
        bf[i] = *(const s16x8*)((const char*)Bs + rb*128 + ((ks*64 + g*16) ^ ((rb&7)<<4)));
      }
      #pragma unroll
      for (int mi=0;mi<4;mi++)
        #pragma unroll
        for (int nj=0;nj<4;nj++)
          acc[mi][nj] = __builtin_amdgcn_mfma_f32_16x16x32_bf16(af[mi], bf[nj], acc[mi][nj], 0, 0, 0);
    }
    __syncthreads();
  }
  #pragma unroll
  for (int mi=0;mi<4;mi++)
    #pragma unroll
    for (int nj=0;nj<4;nj++)
      #pragma unroll
      for (int r=0;r<4;r++){
        int gm = m0 + wr*64 + mi*16 + g*4 + r;
        int gn = n0 + wc*64 + nj*16 + c;
        out[(size_t)gm*1024 + gn] = acc[mi][nj][r];
      }
}

// ---------------- launcher ----------------
extern "C" void kernel_launch(void* const* d_in, const int* in_sizes, int n_in,
                              void* d_out, int out_size, void* d_ws, size_t ws_size,
                              hipStream_t stream)
{
  const float* q  = (const float*)d_in[0];
  const float* k  = (const float*)d_in[1];
  const float* v  = (const float*)d_in[2];
  const unsigned char* mask = (const unsigned char*)d_in[3];
  const float* Wq = (const float*)d_in[4];
  const float* Wk = (const float*)d_in[5];
  const float* Wv = (const float*)d_in[6];
  const float* Wo = (const float*)d_in[7];
  float* out = (float*)d_out;

  char* ws = (char*)d_ws;
  u16* Qp  = (u16*)(ws);                         //  8,388,608 B  [B,H,S,32] bf16
  u16* Kp  = (u16*)(ws + 8388608);               //  8,388,608 B
  u16* Vt  = (u16*)(ws + 16777216);              //  8,388,608 B  [B,H,32,S] bf16
  u16* Z   = (u16*)(ws + 25165824);              //  8,388,608 B  [B*S, 512] bf16
  u16* WT  = (u16*)(ws + 33554432);              //  3,145,728 B  [3][512][1024] bf16
  u16* WoT = (u16*)(ws + 36700160);              //  1,048,576 B  [1024][512] bf16
  u16* mb16 = (u16*)(ws + 37748736);             //  2,097,152 B  mask bits
  int* flag = (int*)(ws + 39845888);

  detect_mask_kernel<<<1, 256, 0, stream>>>(mask, flag);
  pack_mask_kernel<<<4096, 256, 0, stream>>>(mask, flag, mb16);
  prep_weights_kernel<<<8192, 256, 0, stream>>>(Wq, Wk, Wv, Wo, WT, WoT);
  gemm_proj_kernel<<<dim3(64,4,3), 256, 0, stream>>>(q, k, v, WT, Qp, Kp, Vt);
  attn_kernel<<<1024, 256, 0, stream>>>(Qp, Kp, Vt, (const u32*)mb16, Z);
  gemm_out_kernel<<<dim3(64,8), 256, 0, stream>>>(Z, WoT, out);
  (void)in_sizes; (void)n_in; (void)out_size; (void)ws_size;
}

// Round 15
// 202.492 us; speedup vs baseline: 2.4438x; 1.0098x over previous
//
#include <hip/hip_runtime.h>
#include <hip/hip_bf16.h>
#include <math.h>

// B=4, S=2048, D_MODEL=1024, H=16, HD=32, SCALE=8.0
typedef unsigned short u16;
typedef unsigned int u32;
typedef unsigned long long u64;
typedef __attribute__((ext_vector_type(8))) short s16x8;
typedef __attribute__((ext_vector_type(4))) short s16x4;
typedef __attribute__((ext_vector_type(4))) float f32x4;
typedef __attribute__((ext_vector_type(16))) float f32x16;
typedef __attribute__((ext_vector_type(2))) unsigned int u32x2;

#define DEV static __device__ __forceinline__

DEV u16 f2bf(float f){
  __hip_bfloat16 h = __float2bfloat16(f);
  return *reinterpret_cast<u16*>(&h);
}

DEV u32 cvt_pk_bf16(float lo, float hi_){
  u32 r;
  asm("v_cvt_pk_bf16_f32 %0, %1, %2" : "=v"(r) : "v"(lo), "v"(hi_));
  return r;  // low16 = bf16(lo), high16 = bf16(hi_)
}

// SSA-clean permlane32 swap: returns {a.lo||b.lo, a.hi||b.hi} (verified R3->R4 pass)
DEV u32x2 pl32swap(u32 a, u32 b){
  return __builtin_amdgcn_permlane32_swap(a, b, false, false);
}
DEV float xhalf_sum(float x){
  u32x2 r = pl32swap(__float_as_uint(x), __float_as_uint(x));
  return __uint_as_float(r[0]) + __uint_as_float(r[1]);
}

// masked-zero: ext = sext(bit CPOS of msn) (msn = ~mask, so unmasked -> -1 keep, masked -> 0)
template<int CPOS> DEV float mzero(float p, u32 msn){
  int ext;
  asm("v_bfe_i32 %0, %1, %2, 1" : "=v"(ext) : "v"(msn), "n"(CPOS));
  return __uint_as_float(__float_as_uint(p) & (u32)ext);
}

// async global->LDS, 16B per lane; LDS dest = wave-uniform base + lane*16, global src per-lane
// (verified on-device R12/R14; use only on coalesced row-chunk sources — scattered sources
// defeat L2 reuse, see R12 post-mortem)
DEV void gload16(const u16* g, u16* l){
  __builtin_amdgcn_global_load_lds((const __attribute__((address_space(1))) void*)g,
                                   (__attribute__((address_space(3))) void*)l, 16, 0, 0);
}

// ---------------- merged prologue: mask detect+pack AND weight prep in one kernel ----------------
// blocks [0, 4096)        : mask bit-pack (16 bools/thread -> u16), per-block redundant dtype detect
// blocks [4096, 12288)    : weight transpose + bf16 convert (Wq pre-scaled by 0.125*log2(e))
__global__ __launch_bounds__(256) void prep_pack_kernel(
    const unsigned char* __restrict__ m,
    const float* __restrict__ Wq, const float* __restrict__ Wk, const float* __restrict__ Wv,
    const float* __restrict__ Wo, u16* __restrict__ WT, u16* __restrict__ WoT,
    u16* __restrict__ mb16)
{
  const int bid = blockIdx.x;
  if (bid < 4096){
    // per-block mask dtype detect: sample bytes 1,5,9,... of the first 16 KB (L2-resident,
    // identical for all blocks). bool mask -> some byte at i*4+1 is 1; int32 mask(LSB) -> all 0.
    __shared__ int anynz;
    if (threadIdx.x==0) anynz = 0;
    __syncthreads();
    int nz = 0;
    for (int i=threadIdx.x; i<4096; i+=256) nz |= (m[(size_t)i*4+1] != 0) ? 1 : 0;
    if (nz) atomicOr(&anynz, 1);
    __syncthreads();
    const int stride = anynz ? 1 : 4;

    const size_t gid = (size_t)bid*256u + threadIdx.x;   // 1,048,576 threads total
    u32 bits = 0;
    if (stride == 1){
      const uint4 v = *(const uint4*)(m + gid*16);
      bits  =  ((v.x & 0x01010101u) * 0x01020408u) >> 24;
      bits |= (((v.y & 0x01010101u) * 0x01020408u) >> 24) << 4;
      bits |= (((v.z & 0x01010101u) * 0x01020408u) >> 24) << 8;
      bits |= (((v.w & 0x01010101u) * 0x01020408u) >> 24) << 12;
    } else {
      const unsigned char* mm = m + gid*64;
      const uint4 a = *(const uint4*)(mm);
      const uint4 b = *(const uint4*)(mm+16);
      const uint4 c = *(const uint4*)(mm+32);
      const uint4 d = *(const uint4*)(mm+48);
      bits  = (u32)(a.x!=0) | ((u32)(a.y!=0)<<1) | ((u32)(a.z!=0)<<2) | ((u32)(a.w!=0)<<3)
            | ((u32)(b.x!=0)<<4) | ((u32)(b.y!=0)<<5) | ((u32)(b.z!=0)<<6) | ((u32)(b.w!=0)<<7)
            | ((u32)(c.x!=0)<<8) | ((u32)(c.y!=0)<<9) | ((u32)(c.z!=0)<<10)| ((u32)(c.w!=0)<<11)
            | ((u32)(d.x!=0)<<12)| ((u32)(d.y!=0)<<13)| ((u32)(d.z!=0)<<14)| ((u32)(d.w!=0)<<15);
    }
    mb16[gid] = (u16)bits;
  } else {
    int gid = (bid - 4096)*256 + threadIdx.x;
    if (gid < 3*512*1024){
      int z = gid >> 19;
      int r = gid & ((1<<19)-1);
      int n = r >> 10, d = r & 1023;
      const float* W = (z==0)?Wq:((z==1)?Wk:Wv);
      int h = n>>5, e = n&31;
      float wv = W[((size_t)h*1024 + (size_t)d)*32 + e];
      if (z==0) wv *= 0.18033688011112042f;   // (1/sqrt(64)) * log2(e)
      WT[gid] = f2bf(wv);
    } else {
      int r = gid - 3*512*1024;
      int n = r >> 9, cc = r & 511;
      WoT[r] = f2bf(Wo[(size_t)cc*1024 + n]);
    }
  }
}

// ---------------- projection GEMM: [8192x1024]f32 x WT[n][k] -> Q/K (bf16 [B,H,S,32]) or V^T (bf16 [B,H,32,S])
// B staged via global_load_lds with inverse-swizzled per-lane global source (linear LDS dest).
__global__ __launch_bounds__(256) void gemm_proj_kernel(
    const float* __restrict__ Aq, const float* __restrict__ Ak, const float* __restrict__ Av,
    const u16* __restrict__ WT, u16* __restrict__ Qp, u16* __restrict__ Kp, u16* __restrict__ Vt)
{
  __shared__ u16 As[128*64];
  __shared__ u16 Bs[128*64];
  const int z = blockIdx.z;
  const float* __restrict__ A = (z==0)?Aq:((z==1)?Ak:Av);
  const u16* __restrict__ W = WT + (size_t)z*(512*1024);
  const int m0 = blockIdx.x*128, n0 = blockIdx.y*128;
  const int t = threadIdx.x, lane = t&63, wv = t>>6;
  const int wr = wv>>1, wc = wv&1;
  const int c = lane&15, g = lane>>4;
  f32x4 acc[4][4] = {};
  for (int kk=0; kk<1024; kk+=64){
    // B: global_load_lds, linear LDS dest, source pre-swizzled so reads keep the XOR layout
    #pragma unroll
    for (int j=0;j<4;j++){
      const int chunk = j*4 + wv;                 // 16 x 1KB chunks
      const int idx2 = chunk*64 + lane;           // 0..1023
      const int n = idx2>>3, cb = (idx2&7)<<4;    // dest row, dest 16B block
      const int koff = (cb ^ ((n&7)<<4)) >> 1;    // source element offset within row
      gload16(W + (size_t)(n0+n)*1024 + kk + koff, (u16*)((char*)Bs + chunk*1024));
    }
    #pragma unroll
    for (int j=0;j<8;j++){                       // A: 128x64 f32 -> bf16 LDS (swizzled), cvt_pk packing
      int idx = t + j*256;
      int row = idx>>4, kq=(idx&15)<<2;
      f32x4 a4 = *(const f32x4*)(A + (size_t)(m0+row)*1024 + kk + kq);
      u32x2 w2;
      w2[0] = cvt_pk_bf16(a4[0], a4[1]);
      w2[1] = cvt_pk_bf16(a4[2], a4[3]);
      int co = (kq<<1) ^ ((row&7)<<4);
      *(u32x2*)((char*)As + row*128 + co) = w2;
    }
    __syncthreads();
    #pragma unroll
    for (int ks=0;ks<2;ks++){
      s16x8 af[4], bf[4];
      #pragma unroll
      for (int i=0;i<4;i++){
        int ra = wr*64 + i*16 + c;
        af[i] = *(const s16x8*)((const char*)As + ra*128 + ((ks*64 + g*16) ^ ((ra&7)<<4)));
        int rb = wc*64 + i*16 + c;
        bf[i] = *(const s16x8*)((const char*)Bs + rb*128 + ((ks*64 + g*16) ^ ((rb&7)<<4)));
      }
      #pragma unroll
      for (int mi=0;mi<4;mi++)
        #pragma unroll
        for (int nj=0;nj<4;nj++)
          acc[mi][nj] = __builtin_amdgcn_mfma_f32_16x16x32_bf16(af[mi], bf[nj], acc[mi][nj], 0, 0, 0);
    }
    __syncthreads();
  }
  #pragma unroll
  for (int mi=0;mi<4;mi++){
    #pragma unroll
    for (int nj=0;nj<4;nj++){
      #pragma unroll
      for (int r=0;r<4;r++){
        int gm = m0 + wr*64 + mi*16 + g*4 + r;
        int gn = n0 + wc*64 + nj*16 + c;
        u16 val = f2bf(acc[mi][nj][r]);
        int b = gm>>11, s = gm&2047, hh = gn>>5, e = gn&31;
        if (z==0)      Qp[((size_t)(b*16+hh)*2048 + s)*32 + e] = val;
        else if (z==1) Kp[((size_t)(b*16+hh)*2048 + s)*32 + e] = val;
        else           Vt[((size_t)(b*16+hh)*32 + e)*2048 + s] = val;
      }
    }
  }
}

// ---------------- flash attention: swapped 32x32, no-max exp2 softmax, even/odd dual chains (R7/R13 exact) ----
__global__ __launch_bounds__(256, 4) void attn_kernel(
    const u16* __restrict__ Qp, const u16* __restrict__ Kp, const u16* __restrict__ Vt,
    const u32* __restrict__ mb32, u16* __restrict__ Z)
{
  __shared__ float Osh[4][32][36];
  const int t = threadIdx.x, lane = t&63, wid = t>>6;
  const int c = lane&31, hi = lane>>5;
  const int hi8 = hi*8;
  // XCD-aware swizzle: all 16 q-tiles of one bh land on one XCD
  const int wg = blockIdx.x;            // 0..1023
  const int xcd = wg & 7, loc = wg >> 3;
  const int bh = xcd*8 + (loc>>4);
  const int qb = loc & 15;
  const int b = bh>>4, h = bh&15;
  const int q0 = qb*128 + wid*32;
  const u16* Qh = Qp + (size_t)bh*2048*32;
  const u16* Kh = Kp + (size_t)bh*2048*32;
  const u16* Vh = Vt + (size_t)bh*32*2048;

  // Q B-frag: col=q=c, k-dim = hd  (Q pre-scaled by 0.125*log2e)
  const s16x8 qf0 = *(const s16x8*)(Qh + (size_t)(q0 + c)*32 + hi8);
  const s16x8 qf1 = *(const s16x8*)(Qh + (size_t)(q0 + c)*32 + 16 + hi8);

  const f32x16 z16 = {0,0,0,0,0,0,0,0,0,0,0,0,0,0,0,0};
  f32x16 OA = z16, OB = z16;
  f32x4 LA = {0,0,0,0}, LB = {0,0,0,0};
  const u32* mrowp = mb32 + ((size_t)b*2048 + (size_t)(q0 + c))*64;  // 64 u32 words per q-row

  for (int kt = 0; kt < 64; kt += 2){
    const int kbA = kt*32, kbB = kbA + 32;
    // ---- loads for both chains (independent) ----
    const u16* kbaseA = Kh + (size_t)(kbA + c)*32 + hi8;
    const s16x8 kfA0 = *(const s16x8*)(kbaseA);
    const s16x8 kfA1 = *(const s16x8*)(kbaseA + 16);
    const u16* kbaseB = Kh + (size_t)(kbB + c)*32 + hi8;
    const s16x8 kfB0 = *(const s16x8*)(kbaseB);
    const s16x8 kfB1 = *(const s16x8*)(kbaseB + 16);
    const u16* vbase = Vh + (size_t)c*2048 + kbA + hi8;
    const s16x8 vfA0 = *(const s16x8*)(vbase);
    const s16x8 vfA1 = *(const s16x8*)(vbase + 16);
    const s16x8 vfB0 = *(const s16x8*)(vbase + 32);
    const s16x8 vfB1 = *(const s16x8*)(vbase + 48);
    const u64 mw = *(const u64*)(mrowp + kt);
    const u32 msnA = ~(((u32)mw) >> (4*hi));
    const u32 msnB = ~(((u32)(mw >> 32)) >> (4*hi));

    // ---- QK^T (swapped): independent accumulator chains ----
    f32x16 pA = __builtin_amdgcn_mfma_f32_32x32x16_bf16(kfA0, qf0, z16, 0, 0, 0);
    pA = __builtin_amdgcn_mfma_f32_32x32x16_bf16(kfA1, qf1, pA, 0, 0, 0);
    f32x16 pB = __builtin_amdgcn_mfma_f32_32x32x16_bf16(kfB0, qf0, z16, 0, 0, 0);
    pB = __builtin_amdgcn_mfma_f32_32x32x16_bf16(kfB1, qf1, pB, 0, 0, 0);

    // p = exp2(s); zero masked (bit of msn==0 -> masked -> 0)
    #define MZE(P,R,MS) P[R] = mzero<(((R)&3)+8*((R)>>2))>(__builtin_amdgcn_exp2f(P[R]), MS)
    MZE(pA,0,msnA);  MZE(pA,1,msnA);  MZE(pA,2,msnA);  MZE(pA,3,msnA);
    MZE(pA,4,msnA);  MZE(pA,5,msnA);  MZE(pA,6,msnA);  MZE(pA,7,msnA);
    MZE(pA,8,msnA);  MZE(pA,9,msnA);  MZE(pA,10,msnA); MZE(pA,11,msnA);
    MZE(pA,12,msnA); MZE(pA,13,msnA); MZE(pA,14,msnA); MZE(pA,15,msnA);
    MZE(pB,0,msnB);  MZE(pB,1,msnB);  MZE(pB,2,msnB);  MZE(pB,3,msnB);
    MZE(pB,4,msnB);  MZE(pB,5,msnB);  MZE(pB,6,msnB);  MZE(pB,7,msnB);
    MZE(pB,8,msnB);  MZE(pB,9,msnB);  MZE(pB,10,msnB); MZE(pB,11,msnB);
    MZE(pB,12,msnB); MZE(pB,13,msnB); MZE(pB,14,msnB); MZE(pB,15,msnB);
    #undef MZE

    // ---- l partial sums via VALU (off critical path, 4 accumulators per chain) ----
    #pragma unroll
    for (int i=0;i<4;i++){
      LA[i] += (pA[i] + pA[i+4]) + (pA[i+8] + pA[i+12]);
      LB[i] += (pB[i] + pB[i+4]) + (pB[i+8] + pB[i+12]);
    }

    // ---- P^T B-frags: cvt_pk pairs + permlane swaps (wiring verified R3/R4) ----
    u32 pwA0 = cvt_pk_bf16(pA[0],  pA[1]);
    u32 pwA1 = cvt_pk_bf16(pA[2],  pA[3]);
    u32 pwA2 = cvt_pk_bf16(pA[4],  pA[5]);
    u32 pwA3 = cvt_pk_bf16(pA[6],  pA[7]);
    u32 pwA4 = cvt_pk_bf16(pA[8],  pA[9]);
    u32 pwA5 = cvt_pk_bf16(pA[10], pA[11]);
    u32 pwA6 = cvt_pk_bf16(pA[12], pA[13]);
    u32 pwA7 = cvt_pk_bf16(pA[14], pA[15]);
    u32x2 a02 = pl32swap(pwA0, pwA2);
    u32x2 a13 = pl32swap(pwA1, pwA3);
    u32x2 a46 = pl32swap(pwA4, pwA6);
    u32x2 a57 = pl32swap(pwA5, pwA7);
    union { u32 u[4]; s16x8 v; } fA0 = {{a02[0], a13[0], a02[1], a13[1]}};
    union { u32 u[4]; s16x8 v; } fA1 = {{a46[0], a57[0], a46[1], a57[1]}};
    u32 pwB0 = cvt_pk_bf16(pB[0],  pB[1]);
    u32 pwB1 = cvt_pk_bf16(pB[2],  pB[3]);
    u32 pwB2 = cvt_pk_bf16(pB[4],  pB[5]);
    u32 pwB3 = cvt_pk_bf16(pB[6],  pB[7]);
    u32 pwB4 = cvt_pk_bf16(pB[8],  pB[9]);
    u32 pwB5 = cvt_pk_bf16(pB[10], pB[11]);
    u32 pwB6 = cvt_pk_bf16(pB[12], pB[13]);
    u32 pwB7 = cvt_pk_bf16(pB[14], pB[15]);
    u32x2 b02 = pl32swap(pwB0, pwB2);
    u32x2 b13 = pl32swap(pwB1, pwB3);
    u32x2 b46 = pl32swap(pwB4, pwB6);
    u32x2 b57 = pl32swap(pwB5, pwB7);
    union { u32 u[4]; s16x8 v; } fB0 = {{b02[0], b13[0], b02[1], b13[1]}};
    union { u32 u[4]; s16x8 v; } fB1 = {{b46[0], b57[0], b46[1], b57[1]}};

    // ---- PV: independent accumulators ----
    OA = __builtin_amdgcn_mfma_f32_32x32x16_bf16(vfA0, fA0.v, OA, 0, 0, 0);
    OA = __builtin_amdgcn_mfma_f32_32x32x16_bf16(vfA1, fA1.v, OA, 0, 0, 0);
    OB = __builtin_amdgcn_mfma_f32_32x32x16_bf16(vfB0, fB0.v, OB, 0, 0, 0);
    OB = __builtin_amdgcn_mfma_f32_32x32x16_bf16(vfB1, fB1.v, OB, 0, 0, 0);
  }

  // epilogue: merge chains, total l, normalize, transpose via LDS, store
  const float lown = ((LA[0]+LB[0]) + (LA[1]+LB[1])) + ((LA[2]+LB[2]) + (LA[3]+LB[3]));
  const float linv = 1.0f / xhalf_sum(lown);
  #pragma unroll
  for (int r=0;r<16;r++){
    const int hd = (r&3) + 8*(r>>2) + 4*hi;
    Osh[wid][c][hd] = (OA[r] + OB[r]) * linv;
  }
  __syncthreads();
  const int rq = lane >> 1, rc0 = (lane & 1)*16;
  const float* orow = &Osh[wid][rq][0];
  union { u16 q[8]; s16x8 v; } o0, o1;
  #pragma unroll
  for (int j=0;j<8;j++){ o0.q[j] = f2bf(orow[rc0+j]); o1.q[j] = f2bf(orow[rc0+8+j]); }
  u16* zp = Z + ((size_t)b*2048 + (size_t)(q0 + rq))*512 + h*32 + rc0;
  *(s16x8*)(zp)   = o0.v;
  *(s16x8*)(zp+8) = o1.v;
}

// ---------------- output GEMM: Z[8192x512]bf16 x WoT[1024][512] -> out f32 ----------------
// Both operands staged via global_load_lds (linear LDS dest, inverse-swizzled global source).
__global__ __launch_bounds__(256) void gemm_out_kernel(
    const u16* __restrict__ Zb, const u16* __restrict__ WoT, float* __restrict__ out)
{
  __shared__ u16 As[128*64];
  __shared__ u16 Bs[128*64];
  const int m0 = blockIdx.x*128, n0 = blockIdx.y*128;
  const int t = threadIdx.x, lane=t&63, wv=t>>6;
  const int wr=wv>>1, wc=wv&1, c=lane&15, g=lane>>4;
  f32x4 acc[4][4] = {};
  for (int kk=0; kk<512; kk+=64){
    #pragma unroll
    for (int j=0;j<4;j++){
      const int chunk = j*4 + wv;                 // 16 x 1KB chunks per tile
      const int idx2 = chunk*64 + lane;           // 0..1023
      const int n = idx2>>3, cb = (idx2&7)<<4;
      const int koff = (cb ^ ((n&7)<<4)) >> 1;
      gload16(Zb  + (size_t)(m0+n)*512 + kk + koff, (u16*)((char*)As + chunk*1024));
      gload16(WoT + (size_t)(n0+n)*512 + kk + koff, (u16*)((char*)Bs + chunk*1024));
    }
    __syncthreads();
    #pragma unroll
    for (int ks=0;ks<2;ks++){
      s16x8 af[4], bf[4];
      #pragma unroll
      for (int i=0;i<4;i++){
        int ra = wr*64 + i*16 + c;
        af[i] = *(const s16x8*)((const char*)As + ra*128 + ((ks*64 + g*16) ^ ((ra&7)<<4)));
        int rb = wc*64 + i*16 + c;
        bf[i] = *(const s16x8*)((const char*)Bs + rb*128 + ((ks*64 + g*16) ^ ((rb&7)<<4)));
      }
      #pragma unroll
      for (int mi=0;mi<4;mi++)
        #pragma unroll
        for (int nj=0;nj<4;nj++)
          acc[mi][nj] = __builtin_amdgcn_mfma_f32_16x16x32_bf16(af[mi], bf[nj], acc[mi][nj], 0, 0, 0);
    }
    __syncthreads();
  }
  #pragma unroll
  for (int mi=0;mi<4;mi++)
    #pragma unroll
    for (int nj=0;nj<4;nj++)
      #pragma unroll
      for (int r=0;r<4;r++){
        int gm = m0 + wr*64 + mi*16 + g*4 + r;
        int gn = n0 + wc*64 + nj*16 + c;
        out[(size_t)gm*1024 + gn] = acc[mi][nj][r];
      }
}

// ---------------- launcher ----------------
extern "C" void kernel_launch(void* const* d_in, const int* in_sizes, int n_in,
                              void* d_out, int out_size, void* d_ws, size_t ws_size,
                              hipStream_t stream)
{
  const float* q  = (const float*)d_in[0];
  const float* k  = (const float*)d_in[1];
  const float* v  = (const float*)d_in[2];
  const unsigned char* mask = (const unsigned char*)d_in[3];
  const float* Wq = (const float*)d_in[4];
  const float* Wk = (const float*)d_in[5];
  const float* Wv = (const float*)d_in[6];
  const float* Wo = (const float*)d_in[7];
  float* out = (float*)d_out;

  char* ws = (char*)d_ws;
  u16* Qp  = (u16*)(ws);                         //  8,388,608 B  [B,H,S,32] bf16
  u16* Kp  = (u16*)(ws + 8388608);               //  8,388,608 B
  u16* Vt  = (u16*)(ws + 16777216);              //  8,388,608 B  [B,H,32,S] bf16
  u16* Z   = (u16*)(ws + 25165824);              //  8,388,608 B  [B*S, 512] bf16
  u16* WT  = (u16*)(ws + 33554432);              //  3,145,728 B  [3][512][1024] bf16
  u16* WoT = (u16*)(ws + 36700160);              //  1,048,576 B  [1024][512] bf16
  u16* mb16 = (u16*)(ws + 37748736);             //  2,097,152 B  mask bits

  prep_pack_kernel<<<12288, 256, 0, stream>>>(mask, Wq, Wk, Wv, Wo, WT, WoT, mb16);
  gemm_proj_kernel<<<dim3(64,4,3), 256, 0, stream>>>(q, k, v, WT, Qp, Kp, Vt);
  attn_kernel<<<1024, 256, 0, stream>>>(Qp, Kp, Vt, (const u32*)mb16, Z);
  gemm_out_kernel<<<dim3(64,8), 256, 0, stream>>>(Z, WoT, out);
  (void)in_sizes; (void)n_in; (void)out_size; (void)ws_size;
}